// Round 7
// baseline (422.367 us; speedup 1.0000x reference)
//
#include <hip/hip_runtime.h>
#include <math.h>

// Problem constants (fixed by the reference file)
#define NND 100000            // nodes
#define NED 1600000           // edges (before self-loops)
#define TOTE (NND + NED)      // edges + self-loops

#define SCAN_BS 256
#define SCAN_NB ((NND + SCAN_BS - 1) / SCAN_BS)   // 391

// Workspace layout (bytes), total ~87.6 MB
//   hb    : N*128 bf16 = 25,600,000   (h in bf16 for the gather)
//   ys    : N*128 f32  = 51,200,000   (relu(agg+bias), input to k_out)
//   a_src : N*4 f32, a_dst : N*4 f32
//   offs  : (N+1) i32; counts : N i32; ssrt : TOTE i32; bsum/bpref : NB i32
#define OFF_HB    ((size_t)0)
#define OFF_YS    ((size_t)25600000)
#define OFF_ASRC  ((size_t)76800000)
#define OFF_ADST  ((size_t)78400000)
#define OFF_OFFS  ((size_t)80000000)
#define OFF_CNT   ((size_t)80400016)
#define OFF_SRT   ((size_t)80800016)
#define OFF_BSUM  ((size_t)87600016)
#define OFF_BPREF ((size_t)87604016)

__device__ __forceinline__ float leaky02(float v) { return v > 0.f ? v : 0.2f * v; }

// f32 -> bf16 with round-to-nearest-even
__device__ __forceinline__ unsigned short f2bf(float f) {
    unsigned u = __float_as_uint(f);
    return (unsigned short)((u + 0x7fffu + ((u >> 16) & 1u)) >> 16);
}

// ---------------------------------------------------------------------------
// CSR build
// ---------------------------------------------------------------------------
__global__ __launch_bounds__(256)
void k_count_init(int* __restrict__ counts) {
    const int i = blockIdx.x * 256 + threadIdx.x;
    if (i < NND) counts[i] = 1;
}

__global__ __launch_bounds__(256)
void k_hist(const int* __restrict__ edst, int* __restrict__ counts) {
    const int e = blockIdx.x * 256 + threadIdx.x;
    if (e < NED) atomicAdd(&counts[edst[e]], 1);
}

__global__ __launch_bounds__(SCAN_BS)
void k_scan_partial(const int* __restrict__ counts, int* __restrict__ bsum) {
    __shared__ int s[SCAN_BS];
    const int t = threadIdx.x;
    const int i = blockIdx.x * SCAN_BS + t;
    s[t] = (i < NND) ? counts[i] : 0;
    __syncthreads();
#pragma unroll
    for (int d = SCAN_BS / 2; d > 0; d >>= 1) {
        if (t < d) s[t] += s[t + d];
        __syncthreads();
    }
    if (t == 0) bsum[blockIdx.x] = s[0];
}

__global__ __launch_bounds__(512)
void k_scan_bsums(const int* __restrict__ bsum, int* __restrict__ bpref) {
    __shared__ int s[512];
    const int t = threadIdx.x;
    const int v0 = (t < SCAN_NB) ? bsum[t] : 0;
    s[t] = v0;
    __syncthreads();
#pragma unroll
    for (int d = 1; d < 512; d <<= 1) {
        int v = (t >= d) ? s[t - d] : 0;
        __syncthreads();
        s[t] += v;
        __syncthreads();
    }
    if (t < SCAN_NB) bpref[t] = s[t] - v0;   // exclusive
}

__global__ __launch_bounds__(SCAN_BS)
void k_scan_final(const int* __restrict__ counts, const int* __restrict__ bpref,
                  int* __restrict__ off) {
    __shared__ int s[SCAN_BS];
    const int t = threadIdx.x;
    const int i = blockIdx.x * SCAN_BS + t;
    const int v0 = (i < NND) ? counts[i] : 0;
    s[t] = v0;
    __syncthreads();
#pragma unroll
    for (int d = 1; d < SCAN_BS; d <<= 1) {
        int v = (t >= d) ? s[t - d] : 0;
        __syncthreads();
        s[t] += v;
        __syncthreads();
    }
    if (i < NND) off[i + 1] = bpref[blockIdx.x] + s[t];
    if (i == 0) off[0] = 0;
}

// Random/strided 4B stores on gfx950 write-allocate a 64B line -> 16x write
// amplification (r6: k_scatter WRITE=106MB for 6.8MB payload). Atomics execute
// in L2/memory-side and write exact bytes (r1: 218M atomicAdds = 3.9B each).
// So scatter stores go through atomicExch.
__global__ __launch_bounds__(256)
void k_fill_self(const int* __restrict__ off, int* __restrict__ ssrt,
                 int* __restrict__ counts) {
    const int d = blockIdx.x * 256 + threadIdx.x;
    if (d < NND) { atomicExch(&ssrt[off[d]], d); counts[d] = 1; }
}

__global__ __launch_bounds__(256)
void k_scatter(const int* __restrict__ esrc, const int* __restrict__ edst,
               const int* __restrict__ off, int* __restrict__ counts,
               int* __restrict__ ssrt) {
    const int e = blockIdx.x * 256 + threadIdx.x;
    if (e >= NED) return;
    const int d = edst[e];
    const int pos = off[d] + atomicAdd(&counts[d], 1);
    atomicExch(&ssrt[pos], esrc[e]);
}

// ---------------------------------------------------------------------------
// K1: h = x @ W (bf16 out), fused a_src/a_dst epilogue.
// Round-2-proven core: LDS x-staging, thread j owns W column j in 128 VGPRs
// (k loop FULLY unrolled -> static indices -> registers), 4-row ILP.
// bf16 h written as a plain per-thread ushort store (no shuffle/pack — the
// round-4/5 pack epilogue caused a 256-VGPR spill cliff).
// ---------------------------------------------------------------------------
__global__ __launch_bounds__(128)
void k_gemm1(const float* __restrict__ x, const float* __restrict__ W,
             const float* __restrict__ att_s, const float* __restrict__ att_d,
             unsigned short* __restrict__ hb,
             float* __restrict__ a_src, float* __restrict__ a_dst)
{
    const int j = threadIdx.x;            // output channel 0..127
    const int row0 = blockIdx.x * 32;     // 3125 * 32 == 100000 exactly
    __shared__ float xs[32][128];

    float w[128];
#pragma unroll
    for (int k = 0; k < 128; ++k) w[k] = W[k * 128 + j];
    const float asj = att_s[j];
    const float adj = att_d[j];

#pragma unroll 8
    for (int r = 0; r < 32; ++r)
        xs[r][j] = x[(size_t)(row0 + r) * 128 + j];
    __syncthreads();

    for (int r = 0; r < 32; r += 4) {
        float a0 = 0.f, a1 = 0.f, a2 = 0.f, a3 = 0.f;
#pragma unroll
        for (int k = 0; k < 128; ++k) {
            const float wk = w[k];
            a0 += xs[r + 0][k] * wk;
            a1 += xs[r + 1][k] * wk;
            a2 += xs[r + 2][k] * wk;
            a3 += xs[r + 3][k] * wk;
        }
        const size_t base = (size_t)(row0 + r) * 128 + j;
        hb[base]       = f2bf(a0);
        hb[base + 128] = f2bf(a1);
        hb[base + 256] = f2bf(a2);
        hb[base + 384] = f2bf(a3);

        // attention logits: reduce over the 32 channels of each head
#pragma unroll
        for (int q = 0; q < 4; ++q) {
            const float hv = (q == 0) ? a0 : (q == 1) ? a1 : (q == 2) ? a2 : a3;
            float vs = hv * asj;
            float vd = hv * adj;
#pragma unroll
            for (int off = 16; off > 0; off >>= 1) {
                vs += __shfl_xor(vs, off, 32);
                vd += __shfl_xor(vd, off, 32);
            }
            if ((j & 31) == 0) {
                const int row = row0 + r + q;
                a_src[row * 4 + (j >> 5)] = vs;
                a_dst[row * 4 + (j >> 5)] = vd;
            }
        }
    }
}

// ---------------------------------------------------------------------------
// Fused segment softmax + aggregation + bias + relu. One wave per node.
// src/alpha staged in per-wave LDS; bf16 h gather (1 dword per lane per edge),
// hand-unrolled x4 so loads overlap. (Round-4 version, proven.)
// ---------------------------------------------------------------------------
__global__ __launch_bounds__(256)
void k_fused(const int* __restrict__ off, const int* __restrict__ ssrt,
             const float* __restrict__ a_src, const float* __restrict__ a_dst,
             const unsigned short* __restrict__ hb, const float* __restrict__ bias,
             float* __restrict__ ys)
{
    __shared__ int   s_src[4][64];
    __shared__ float s_alp[4][64][4];
    const int lane = threadIdx.x & 63;
    const int wv = threadIdx.x >> 6;
    const int d = blockIdx.x * 4 + wv;
    if (d >= NND) return;
    const int beg = off[d];
    const int deg = off[d + 1] - beg;
    const float4 ad = *(const float4*)(a_dst + (size_t)d * 4);

    int mysrc = d;
    float4 e4 = make_float4(-1e30f, -1e30f, -1e30f, -1e30f);
    if (lane < deg) {
        mysrc = ssrt[beg + lane];
        const float4 as = *(const float4*)(a_src + (size_t)mysrc * 4);
        e4.x = leaky02(as.x + ad.x);
        e4.y = leaky02(as.y + ad.y);
        e4.z = leaky02(as.z + ad.z);
        e4.w = leaky02(as.w + ad.w);
    }
    float4 mx = e4;
    for (int base = 64; base < deg; base += 64) {
        if (base + lane < deg) {
            const int s = ssrt[beg + base + lane];
            const float4 as = *(const float4*)(a_src + (size_t)s * 4);
            mx.x = fmaxf(mx.x, leaky02(as.x + ad.x));
            mx.y = fmaxf(mx.y, leaky02(as.y + ad.y));
            mx.z = fmaxf(mx.z, leaky02(as.z + ad.z));
            mx.w = fmaxf(mx.w, leaky02(as.w + ad.w));
        }
    }
#pragma unroll
    for (int o = 32; o > 0; o >>= 1) {
        mx.x = fmaxf(mx.x, __shfl_xor(mx.x, o, 64));
        mx.y = fmaxf(mx.y, __shfl_xor(mx.y, o, 64));
        mx.z = fmaxf(mx.z, __shfl_xor(mx.z, o, 64));
        mx.w = fmaxf(mx.w, __shfl_xor(mx.w, o, 64));
    }
    float4 ex = make_float4(0.f, 0.f, 0.f, 0.f);
    if (lane < deg) {
        ex.x = __expf(e4.x - mx.x);
        ex.y = __expf(e4.y - mx.y);
        ex.z = __expf(e4.z - mx.z);
        ex.w = __expf(e4.w - mx.w);
    }
    float4 sm = ex;
    for (int base = 64; base < deg; base += 64) {
        if (base + lane < deg) {
            const int s = ssrt[beg + base + lane];
            const float4 as = *(const float4*)(a_src + (size_t)s * 4);
            sm.x += __expf(leaky02(as.x + ad.x) - mx.x);
            sm.y += __expf(leaky02(as.y + ad.y) - mx.y);
            sm.z += __expf(leaky02(as.z + ad.z) - mx.z);
            sm.w += __expf(leaky02(as.w + ad.w) - mx.w);
        }
    }
#pragma unroll
    for (int o = 32; o > 0; o >>= 1) {
        sm.x += __shfl_xor(sm.x, o, 64);
        sm.y += __shfl_xor(sm.y, o, 64);
        sm.z += __shfl_xor(sm.z, o, 64);
        sm.w += __shfl_xor(sm.w, o, 64);
    }
    const float4 inv = make_float4(1.f / (sm.x + 1e-16f), 1.f / (sm.y + 1e-16f),
                                   1.f / (sm.z + 1e-16f), 1.f / (sm.w + 1e-16f));

    // stage chunk-0 src + alpha in per-wave LDS (wave-coherent, no barrier)
    const int cnt = min(deg, 64);
    if (lane < cnt) {
        s_src[wv][lane] = mysrc;
        const float4 al = make_float4(ex.x * inv.x, ex.y * inv.y,
                                      ex.z * inv.z, ex.w * inv.w);
        *(float4*)&s_alp[wv][lane][0] = al;
    }

    const int hsel = lane >> 4;               // head for channels 2*lane,2*lane+1
    float accx = 0.f, accy = 0.f;
    int k = 0;
    for (; k + 4 <= cnt; k += 4) {
        const int s0 = s_src[wv][k],     s1 = s_src[wv][k + 1];
        const int s2 = s_src[wv][k + 2], s3 = s_src[wv][k + 3];
        const float A0 = s_alp[wv][k][hsel],     A1 = s_alp[wv][k + 1][hsel];
        const float A2 = s_alp[wv][k + 2][hsel], A3 = s_alp[wv][k + 3][hsel];
        const unsigned u0 = *(const unsigned*)(hb + (size_t)s0 * 128 + 2 * lane);
        const unsigned u1 = *(const unsigned*)(hb + (size_t)s1 * 128 + 2 * lane);
        const unsigned u2 = *(const unsigned*)(hb + (size_t)s2 * 128 + 2 * lane);
        const unsigned u3 = *(const unsigned*)(hb + (size_t)s3 * 128 + 2 * lane);
        accx += __uint_as_float(u0 << 16) * A0;
        accy += __uint_as_float(u0 & 0xffff0000u) * A0;
        accx += __uint_as_float(u1 << 16) * A1;
        accy += __uint_as_float(u1 & 0xffff0000u) * A1;
        accx += __uint_as_float(u2 << 16) * A2;
        accy += __uint_as_float(u2 & 0xffff0000u) * A2;
        accx += __uint_as_float(u3 << 16) * A3;
        accy += __uint_as_float(u3 & 0xffff0000u) * A3;
    }
    for (; k < cnt; ++k) {
        const int s = s_src[wv][k];
        const float A = s_alp[wv][k][hsel];
        const unsigned u = *(const unsigned*)(hb + (size_t)s * 128 + 2 * lane);
        accx += __uint_as_float(u << 16) * A;
        accy += __uint_as_float(u & 0xffff0000u) * A;
    }
    // rare deg>64 chunks
    for (int base = 64; base < deg; base += 64) {
        const int c2 = min(64, deg - base);
        if (lane < c2) {
            const int s = ssrt[beg + base + lane];
            const float4 as = *(const float4*)(a_src + (size_t)s * 4);
            float4 al2;
            al2.x = __expf(leaky02(as.x + ad.x) - mx.x) * inv.x;
            al2.y = __expf(leaky02(as.y + ad.y) - mx.y) * inv.y;
            al2.z = __expf(leaky02(as.z + ad.z) - mx.z) * inv.z;
            al2.w = __expf(leaky02(as.w + ad.w) - mx.w) * inv.w;
            s_src[wv][lane] = s;
            *(float4*)&s_alp[wv][lane][0] = al2;
        }
        for (int kk = 0; kk < c2; ++kk) {
            const int s = s_src[wv][kk];
            const float A = s_alp[wv][kk][hsel];
            const unsigned u = *(const unsigned*)(hb + (size_t)s * 128 + 2 * lane);
            accx += __uint_as_float(u << 16) * A;
            accy += __uint_as_float(u & 0xffff0000u) * A;
        }
    }
    // fused bias + relu
    const float2 bb = *(const float2*)(bias + 2 * lane);
    float ox = accx + bb.x, oy = accy + bb.y;
    ox = ox > 0.f ? ox : 0.f;
    oy = oy > 0.f ? oy : 0.f;
    *(float2*)(ys + (size_t)d * 128 + 2 * lane) = make_float2(ox, oy);
}

// ---------------------------------------------------------------------------
// K_out: out = ys @ lin_w + lin_b  (N x 128 @ 128 x 64).
// Round-3 proven structure: LDS ys-staging, w[] in registers (full unroll).
// ---------------------------------------------------------------------------
__global__ __launch_bounds__(128)
void k_out(const float* __restrict__ ys, const float* __restrict__ lin_w,
           const float* __restrict__ lin_b, float* __restrict__ out)
{
    const int t = threadIdx.x;
    const int j = t & 63;
    const int half = t >> 6;
    const int row0 = blockIdx.x * 16;    // 6250 * 16 == 100000 exactly
    __shared__ float yl[16][128];

    float w[128];
#pragma unroll
    for (int k = 0; k < 128; ++k) w[k] = lin_w[(size_t)k * 64 + j];
    const float lb = lin_b[j];

#pragma unroll 4
    for (int r = 0; r < 16; ++r)
        yl[r][t] = ys[(size_t)(row0 + r) * 128 + t];
    __syncthreads();

#pragma unroll
    for (int g = 0; g < 2; ++g) {
        const int rb = g * 8 + half;    // rows rb, rb+2, rb+4, rb+6
        float a0 = 0.f, a1 = 0.f, a2 = 0.f, a3 = 0.f;
#pragma unroll
        for (int k = 0; k < 128; ++k) {
            const float wk = w[k];
            a0 += yl[rb + 0][k] * wk;
            a1 += yl[rb + 2][k] * wk;
            a2 += yl[rb + 4][k] * wk;
            a3 += yl[rb + 6][k] * wk;
        }
        out[(size_t)(row0 + rb + 0) * 64 + j] = a0 + lb;
        out[(size_t)(row0 + rb + 2) * 64 + j] = a1 + lb;
        out[(size_t)(row0 + rb + 4) * 64 + j] = a2 + lb;
        out[(size_t)(row0 + rb + 6) * 64 + j] = a3 + lb;
    }
}

extern "C" void kernel_launch(void* const* d_in, const int* in_sizes, int n_in,
                              void* d_out, int out_size, void* d_ws, size_t ws_size,
                              hipStream_t stream)
{
    const float* x     = (const float*)d_in[0];
    const int*   ei    = (const int*)  d_in[1];   // [2][E] int32
    const float* W     = (const float*)d_in[2];
    const float* att_s = (const float*)d_in[3];
    const float* att_d = (const float*)d_in[4];
    const float* bias  = (const float*)d_in[5];
    const float* lin_w = (const float*)d_in[6];
    const float* lin_b = (const float*)d_in[7];
    float* out = (float*)d_out;

    const int* esrc = ei;        // edge_index[0] = message source
    const int* edst = ei + NED;  // edge_index[1] = message target

    char* ws = (char*)d_ws;
    unsigned short* hb = (unsigned short*)(ws + OFF_HB);
    float* ys    = (float*)(ws + OFF_YS);
    float* a_src = (float*)(ws + OFF_ASRC);
    float* a_dst = (float*)(ws + OFF_ADST);
    int*   offs  = (int*)  (ws + OFF_OFFS);
    int*   cnts  = (int*)  (ws + OFF_CNT);
    int*   ssrt  = (int*)  (ws + OFF_SRT);
    int*   bsum  = (int*)  (ws + OFF_BSUM);
    int*   bpref = (int*)  (ws + OFF_BPREF);

    // CSR build (dst-sorted edge list, self-loop at each segment head)
    k_count_init<<<(NND + 255) / 256, 256, 0, stream>>>(cnts);
    k_hist<<<(NED + 255) / 256, 256, 0, stream>>>(edst, cnts);
    k_scan_partial<<<SCAN_NB, SCAN_BS, 0, stream>>>(cnts, bsum);
    k_scan_bsums<<<1, 512, 0, stream>>>(bsum, bpref);
    k_scan_final<<<SCAN_NB, SCAN_BS, 0, stream>>>(cnts, bpref, offs);
    k_fill_self<<<(NND + 255) / 256, 256, 0, stream>>>(offs, ssrt, cnts);
    k_scatter<<<(NED + 255) / 256, 256, 0, stream>>>(esrc, edst, offs, cnts, ssrt);

    // feature transform + attention logits (bf16 h out)
    k_gemm1<<<NND / 32, 128, 0, stream>>>(x, W, att_s, att_d, hb, a_src, a_dst);

    // fused segment softmax + aggregation + bias + relu
    k_fused<<<(NND + 3) / 4, 256, 0, stream>>>(offs, ssrt, a_src, a_dst, hb, bias, ys);

    // output projection
    k_out<<<NND / 16, 128, 0, stream>>>(ys, lin_w, lin_b, out);
}

// Round 8
// 358.082 us; speedup vs baseline: 1.1795x; 1.1795x over previous
//
#include <hip/hip_runtime.h>
#include <math.h>

// Problem constants (fixed by the reference file)
#define NND 100000            // nodes
#define NED 1600000           // edges (before self-loops)
#define TOTE (NND + NED)      // edges + self-loops

#define SCAN_BS 256
#define SCAN_NB ((NND + SCAN_BS - 1) / SCAN_BS)   // 391

// dst-range-partitioned scatter (one range per XCD)
#define NRANGE 8
#define RNG_NODES ((NND + NRANGE - 1) / NRANGE)   // 12500
#define NCHUNK 640
#define CHUNK_E ((NED + NCHUNK - 1) / NCHUNK)     // 2500

// Workspace layout (bytes), total ~87.6 MB
#define OFF_HB    ((size_t)0)
#define OFF_YS    ((size_t)25600000)
#define OFF_ASRC  ((size_t)76800000)
#define OFF_ADST  ((size_t)78400000)
#define OFF_OFFS  ((size_t)80000000)
#define OFF_CNT   ((size_t)80400016)
#define OFF_SRT   ((size_t)80800016)
#define OFF_BSUM  ((size_t)87600016)
#define OFF_BPREF ((size_t)87604016)

__device__ __forceinline__ float leaky02(float v) { return v > 0.f ? v : 0.2f * v; }

// f32 -> bf16 with round-to-nearest-even
__device__ __forceinline__ unsigned short f2bf(float f) {
    unsigned u = __float_as_uint(f);
    return (unsigned short)((u + 0x7fffu + ((u >> 16) & 1u)) >> 16);
}

// ---------------------------------------------------------------------------
// CSR build
// ---------------------------------------------------------------------------
__global__ __launch_bounds__(256)
void k_count_init(int* __restrict__ counts) {
    const int i = blockIdx.x * 256 + threadIdx.x;
    if (i < NND) counts[i] = 1;
}

__global__ __launch_bounds__(256)
void k_hist(const int* __restrict__ edst, int* __restrict__ counts) {
    const int e = blockIdx.x * 256 + threadIdx.x;
    if (e < NED) atomicAdd(&counts[edst[e]], 1);
}

__global__ __launch_bounds__(SCAN_BS)
void k_scan_partial(const int* __restrict__ counts, int* __restrict__ bsum) {
    __shared__ int s[SCAN_BS];
    const int t = threadIdx.x;
    const int i = blockIdx.x * SCAN_BS + t;
    s[t] = (i < NND) ? counts[i] : 0;
    __syncthreads();
#pragma unroll
    for (int d = SCAN_BS / 2; d > 0; d >>= 1) {
        if (t < d) s[t] += s[t + d];
        __syncthreads();
    }
    if (t == 0) bsum[blockIdx.x] = s[0];
}

__global__ __launch_bounds__(512)
void k_scan_bsums(const int* __restrict__ bsum, int* __restrict__ bpref) {
    __shared__ int s[512];
    const int t = threadIdx.x;
    const int v0 = (t < SCAN_NB) ? bsum[t] : 0;
    s[t] = v0;
    __syncthreads();
#pragma unroll
    for (int d = 1; d < 512; d <<= 1) {
        int v = (t >= d) ? s[t - d] : 0;
        __syncthreads();
        s[t] += v;
        __syncthreads();
    }
    if (t < SCAN_NB) bpref[t] = s[t] - v0;   // exclusive
}

__global__ __launch_bounds__(SCAN_BS)
void k_scan_final(const int* __restrict__ counts, const int* __restrict__ bpref,
                  int* __restrict__ off) {
    __shared__ int s[SCAN_BS];
    const int t = threadIdx.x;
    const int i = blockIdx.x * SCAN_BS + t;
    const int v0 = (i < NND) ? counts[i] : 0;
    s[t] = v0;
    __syncthreads();
#pragma unroll
    for (int d = 1; d < SCAN_BS; d <<= 1) {
        int v = (t >= d) ? s[t - d] : 0;
        __syncthreads();
        s[t] += v;
        __syncthreads();
    }
    if (i < NND) off[i + 1] = bpref[blockIdx.x] + s[t];
    if (i == 0) off[0] = 0;
}

// ---------------------------------------------------------------------------
// Range-partitioned scatter. r6/r7 evidence: random 4B writes to the 6.8MB
// ssrt from all XCDs -> ~15x line-writeback amplification (WRITE ~100MB),
// identical for plain stores and atomicExch (r7 falsified the atomic-bypass
// theory). Fix the mechanism instead: partition dst into 8 ranges (850KB of
// ssrt each, fits one XCD's 4MB L2); block b = (range b%8, edge-chunk b/8),
// matching round-robin block->XCD dispatch. Each ssrt line is then filled
// entirely within one XCD's L2 -> one full-line writeback. Edges re-read 8x
// but the 12.8MB edge list is L3-resident. Self-loops merged into chunk 0.
// ---------------------------------------------------------------------------
__global__ __launch_bounds__(256)
void k_scatter_rng(const int* __restrict__ esrc, const int* __restrict__ edst,
                   const int* __restrict__ off, int* __restrict__ counts,
                   int* __restrict__ ssrt)
{
    const int r = blockIdx.x % NRANGE;
    const int chunk = blockIdx.x / NRANGE;
    const int dlo = r * RNG_NODES;
    const int dhi = min(NND, dlo + RNG_NODES);

    if (chunk == 0) {   // self-loop at each segment head (same L2 range)
        for (int d = dlo + threadIdx.x; d < dhi; d += 256)
            ssrt[off[d]] = d;
    }
    const int elo = chunk * CHUNK_E;
    const int ehi = min(NED, elo + CHUNK_E);
    for (int e = elo + threadIdx.x; e < ehi; e += 256) {
        const int d = edst[e];
        if (d >= dlo && d < dhi) {
            const int pos = off[d] + atomicAdd(&counts[d], 1);
            ssrt[pos] = esrc[e];
        }
    }
}

// ---------------------------------------------------------------------------
// K1: h = x @ W (bf16 out), fused a_src/a_dst epilogue.
// Round-2-proven core: LDS x-staging, thread j owns W column j in 128 VGPRs
// (k loop FULLY unrolled -> static indices -> registers), 4-row ILP.
// bf16 h written as a plain per-thread ushort store (no shuffle/pack — the
// round-4/5 pack epilogue caused a 256-VGPR spill cliff).
// ---------------------------------------------------------------------------
__global__ __launch_bounds__(128)
void k_gemm1(const float* __restrict__ x, const float* __restrict__ W,
             const float* __restrict__ att_s, const float* __restrict__ att_d,
             unsigned short* __restrict__ hb,
             float* __restrict__ a_src, float* __restrict__ a_dst)
{
    const int j = threadIdx.x;            // output channel 0..127
    const int row0 = blockIdx.x * 32;     // 3125 * 32 == 100000 exactly
    __shared__ float xs[32][128];

    float w[128];
#pragma unroll
    for (int k = 0; k < 128; ++k) w[k] = W[k * 128 + j];
    const float asj = att_s[j];
    const float adj = att_d[j];

#pragma unroll 8
    for (int r = 0; r < 32; ++r)
        xs[r][j] = x[(size_t)(row0 + r) * 128 + j];
    __syncthreads();

    for (int r = 0; r < 32; r += 4) {
        float a0 = 0.f, a1 = 0.f, a2 = 0.f, a3 = 0.f;
#pragma unroll
        for (int k = 0; k < 128; ++k) {
            const float wk = w[k];
            a0 += xs[r + 0][k] * wk;
            a1 += xs[r + 1][k] * wk;
            a2 += xs[r + 2][k] * wk;
            a3 += xs[r + 3][k] * wk;
        }
        const size_t base = (size_t)(row0 + r) * 128 + j;
        hb[base]       = f2bf(a0);
        hb[base + 128] = f2bf(a1);
        hb[base + 256] = f2bf(a2);
        hb[base + 384] = f2bf(a3);

        // attention logits: reduce over the 32 channels of each head
#pragma unroll
        for (int q = 0; q < 4; ++q) {
            const float hv = (q == 0) ? a0 : (q == 1) ? a1 : (q == 2) ? a2 : a3;
            float vs = hv * asj;
            float vd = hv * adj;
#pragma unroll
            for (int off = 16; off > 0; off >>= 1) {
                vs += __shfl_xor(vs, off, 32);
                vd += __shfl_xor(vd, off, 32);
            }
            if ((j & 31) == 0) {
                const int row = row0 + r + q;
                a_src[row * 4 + (j >> 5)] = vs;
                a_dst[row * 4 + (j >> 5)] = vd;
            }
        }
    }
}

// ---------------------------------------------------------------------------
// Fused segment softmax + aggregation + bias + relu. One wave per node.
// src/alpha staged in per-wave LDS; bf16 h gather (1 dword per lane per edge),
// hand-unrolled x4 so loads overlap. (Round-4 version, proven.)
// ---------------------------------------------------------------------------
__global__ __launch_bounds__(256)
void k_fused(const int* __restrict__ off, const int* __restrict__ ssrt,
             const float* __restrict__ a_src, const float* __restrict__ a_dst,
             const unsigned short* __restrict__ hb, const float* __restrict__ bias,
             float* __restrict__ ys)
{
    __shared__ int   s_src[4][64];
    __shared__ float s_alp[4][64][4];
    const int lane = threadIdx.x & 63;
    const int wv = threadIdx.x >> 6;
    const int d = blockIdx.x * 4 + wv;
    if (d >= NND) return;
    const int beg = off[d];
    const int deg = off[d + 1] - beg;
    const float4 ad = *(const float4*)(a_dst + (size_t)d * 4);

    int mysrc = d;
    float4 e4 = make_float4(-1e30f, -1e30f, -1e30f, -1e30f);
    if (lane < deg) {
        mysrc = ssrt[beg + lane];
        const float4 as = *(const float4*)(a_src + (size_t)mysrc * 4);
        e4.x = leaky02(as.x + ad.x);
        e4.y = leaky02(as.y + ad.y);
        e4.z = leaky02(as.z + ad.z);
        e4.w = leaky02(as.w + ad.w);
    }
    float4 mx = e4;
    for (int base = 64; base < deg; base += 64) {
        if (base + lane < deg) {
            const int s = ssrt[beg + base + lane];
            const float4 as = *(const float4*)(a_src + (size_t)s * 4);
            mx.x = fmaxf(mx.x, leaky02(as.x + ad.x));
            mx.y = fmaxf(mx.y, leaky02(as.y + ad.y));
            mx.z = fmaxf(mx.z, leaky02(as.z + ad.z));
            mx.w = fmaxf(mx.w, leaky02(as.w + ad.w));
        }
    }
#pragma unroll
    for (int o = 32; o > 0; o >>= 1) {
        mx.x = fmaxf(mx.x, __shfl_xor(mx.x, o, 64));
        mx.y = fmaxf(mx.y, __shfl_xor(mx.y, o, 64));
        mx.z = fmaxf(mx.z, __shfl_xor(mx.z, o, 64));
        mx.w = fmaxf(mx.w, __shfl_xor(mx.w, o, 64));
    }
    float4 ex = make_float4(0.f, 0.f, 0.f, 0.f);
    if (lane < deg) {
        ex.x = __expf(e4.x - mx.x);
        ex.y = __expf(e4.y - mx.y);
        ex.z = __expf(e4.z - mx.z);
        ex.w = __expf(e4.w - mx.w);
    }
    float4 sm = ex;
    for (int base = 64; base < deg; base += 64) {
        if (base + lane < deg) {
            const int s = ssrt[beg + base + lane];
            const float4 as = *(const float4*)(a_src + (size_t)s * 4);
            sm.x += __expf(leaky02(as.x + ad.x) - mx.x);
            sm.y += __expf(leaky02(as.y + ad.y) - mx.y);
            sm.z += __expf(leaky02(as.z + ad.z) - mx.z);
            sm.w += __expf(leaky02(as.w + ad.w) - mx.w);
        }
    }
#pragma unroll
    for (int o = 32; o > 0; o >>= 1) {
        sm.x += __shfl_xor(sm.x, o, 64);
        sm.y += __shfl_xor(sm.y, o, 64);
        sm.z += __shfl_xor(sm.z, o, 64);
        sm.w += __shfl_xor(sm.w, o, 64);
    }
    const float4 inv = make_float4(1.f / (sm.x + 1e-16f), 1.f / (sm.y + 1e-16f),
                                   1.f / (sm.z + 1e-16f), 1.f / (sm.w + 1e-16f));

    // stage chunk-0 src + alpha in per-wave LDS (wave-coherent, no barrier)
    const int cnt = min(deg, 64);
    if (lane < cnt) {
        s_src[wv][lane] = mysrc;
        const float4 al = make_float4(ex.x * inv.x, ex.y * inv.y,
                                      ex.z * inv.z, ex.w * inv.w);
        *(float4*)&s_alp[wv][lane][0] = al;
    }

    const int hsel = lane >> 4;               // head for channels 2*lane,2*lane+1
    float accx = 0.f, accy = 0.f;
    int k = 0;
    for (; k + 4 <= cnt; k += 4) {
        const int s0 = s_src[wv][k],     s1 = s_src[wv][k + 1];
        const int s2 = s_src[wv][k + 2], s3 = s_src[wv][k + 3];
        const float A0 = s_alp[wv][k][hsel],     A1 = s_alp[wv][k + 1][hsel];
        const float A2 = s_alp[wv][k + 2][hsel], A3 = s_alp[wv][k + 3][hsel];
        const unsigned u0 = *(const unsigned*)(hb + (size_t)s0 * 128 + 2 * lane);
        const unsigned u1 = *(const unsigned*)(hb + (size_t)s1 * 128 + 2 * lane);
        const unsigned u2 = *(const unsigned*)(hb + (size_t)s2 * 128 + 2 * lane);
        const unsigned u3 = *(const unsigned*)(hb + (size_t)s3 * 128 + 2 * lane);
        accx += __uint_as_float(u0 << 16) * A0;
        accy += __uint_as_float(u0 & 0xffff0000u) * A0;
        accx += __uint_as_float(u1 << 16) * A1;
        accy += __uint_as_float(u1 & 0xffff0000u) * A1;
        accx += __uint_as_float(u2 << 16) * A2;
        accy += __uint_as_float(u2 & 0xffff0000u) * A2;
        accx += __uint_as_float(u3 << 16) * A3;
        accy += __uint_as_float(u3 & 0xffff0000u) * A3;
    }
    for (; k < cnt; ++k) {
        const int s = s_src[wv][k];
        const float A = s_alp[wv][k][hsel];
        const unsigned u = *(const unsigned*)(hb + (size_t)s * 128 + 2 * lane);
        accx += __uint_as_float(u << 16) * A;
        accy += __uint_as_float(u & 0xffff0000u) * A;
    }
    // rare deg>64 chunks
    for (int base = 64; base < deg; base += 64) {
        const int c2 = min(64, deg - base);
        if (lane < c2) {
            const int s = ssrt[beg + base + lane];
            const float4 as = *(const float4*)(a_src + (size_t)s * 4);
            float4 al2;
            al2.x = __expf(leaky02(as.x + ad.x) - mx.x) * inv.x;
            al2.y = __expf(leaky02(as.y + ad.y) - mx.y) * inv.y;
            al2.z = __expf(leaky02(as.z + ad.z) - mx.z) * inv.z;
            al2.w = __expf(leaky02(as.w + ad.w) - mx.w) * inv.w;
            s_src[wv][lane] = s;
            *(float4*)&s_alp[wv][lane][0] = al2;
        }
        for (int kk = 0; kk < c2; ++kk) {
            const int s = s_src[wv][kk];
            const float A = s_alp[wv][kk][hsel];
            const unsigned u = *(const unsigned*)(hb + (size_t)s * 128 + 2 * lane);
            accx += __uint_as_float(u << 16) * A;
            accy += __uint_as_float(u & 0xffff0000u) * A;
        }
    }
    // fused bias + relu
    const float2 bb = *(const float2*)(bias + 2 * lane);
    float ox = accx + bb.x, oy = accy + bb.y;
    ox = ox > 0.f ? ox : 0.f;
    oy = oy > 0.f ? oy : 0.f;
    *(float2*)(ys + (size_t)d * 128 + 2 * lane) = make_float2(ox, oy);
}

// ---------------------------------------------------------------------------
// K_out: out = ys @ lin_w + lin_b  (N x 128 @ 128 x 64).
// Round-3 proven structure: LDS ys-staging, w[] in registers (full unroll).
// ---------------------------------------------------------------------------
__global__ __launch_bounds__(128)
void k_out(const float* __restrict__ ys, const float* __restrict__ lin_w,
           const float* __restrict__ lin_b, float* __restrict__ out)
{
    const int t = threadIdx.x;
    const int j = t & 63;
    const int half = t >> 6;
    const int row0 = blockIdx.x * 16;    // 6250 * 16 == 100000 exactly
    __shared__ float yl[16][128];

    float w[128];
#pragma unroll
    for (int k = 0; k < 128; ++k) w[k] = lin_w[(size_t)k * 64 + j];
    const float lb = lin_b[j];

#pragma unroll 4
    for (int r = 0; r < 16; ++r)
        yl[r][t] = ys[(size_t)(row0 + r) * 128 + t];
    __syncthreads();

#pragma unroll
    for (int g = 0; g < 2; ++g) {
        const int rb = g * 8 + half;    // rows rb, rb+2, rb+4, rb+6
        float a0 = 0.f, a1 = 0.f, a2 = 0.f, a3 = 0.f;
#pragma unroll
        for (int k = 0; k < 128; ++k) {
            const float wk = w[k];
            a0 += yl[rb + 0][k] * wk;
            a1 += yl[rb + 2][k] * wk;
            a2 += yl[rb + 4][k] * wk;
            a3 += yl[rb + 6][k] * wk;
        }
        out[(size_t)(row0 + rb + 0) * 64 + j] = a0 + lb;
        out[(size_t)(row0 + rb + 2) * 64 + j] = a1 + lb;
        out[(size_t)(row0 + rb + 4) * 64 + j] = a2 + lb;
        out[(size_t)(row0 + rb + 6) * 64 + j] = a3 + lb;
    }
}

extern "C" void kernel_launch(void* const* d_in, const int* in_sizes, int n_in,
                              void* d_out, int out_size, void* d_ws, size_t ws_size,
                              hipStream_t stream)
{
    const float* x     = (const float*)d_in[0];
    const int*   ei    = (const int*)  d_in[1];   // [2][E] int32
    const float* W     = (const float*)d_in[2];
    const float* att_s = (const float*)d_in[3];
    const float* att_d = (const float*)d_in[4];
    const float* bias  = (const float*)d_in[5];
    const float* lin_w = (const float*)d_in[6];
    const float* lin_b = (const float*)d_in[7];
    float* out = (float*)d_out;

    const int* esrc = ei;        // edge_index[0] = message source
    const int* edst = ei + NED;  // edge_index[1] = message target

    char* ws = (char*)d_ws;
    unsigned short* hb = (unsigned short*)(ws + OFF_HB);
    float* ys    = (float*)(ws + OFF_YS);
    float* a_src = (float*)(ws + OFF_ASRC);
    float* a_dst = (float*)(ws + OFF_ADST);
    int*   offs  = (int*)  (ws + OFF_OFFS);
    int*   cnts  = (int*)  (ws + OFF_CNT);
    int*   ssrt  = (int*)  (ws + OFF_SRT);
    int*   bsum  = (int*)  (ws + OFF_BSUM);
    int*   bpref = (int*)  (ws + OFF_BPREF);

    // CSR build (dst-sorted edge list, self-loop at each segment head)
    k_count_init<<<(NND + 255) / 256, 256, 0, stream>>>(cnts);
    k_hist<<<(NED + 255) / 256, 256, 0, stream>>>(edst, cnts);
    k_scan_partial<<<SCAN_NB, SCAN_BS, 0, stream>>>(cnts, bsum);
    k_scan_bsums<<<1, 512, 0, stream>>>(bsum, bpref);
    k_scan_final<<<SCAN_NB, SCAN_BS, 0, stream>>>(cnts, bpref, offs);
    k_count_init<<<(NND + 255) / 256, 256, 0, stream>>>(cnts);  // reset cursors
    k_scatter_rng<<<NRANGE * NCHUNK, 256, 0, stream>>>(esrc, edst, offs, cnts, ssrt);

    // feature transform + attention logits (bf16 h out)
    k_gemm1<<<NND / 32, 128, 0, stream>>>(x, W, att_s, att_d, hb, a_src, a_dst);

    // fused segment softmax + aggregation + bias + relu
    k_fused<<<(NND + 3) / 4, 256, 0, stream>>>(offs, ssrt, a_src, a_dst, hb, bias, ys);

    // output projection
    k_out<<<NND / 16, 128, 0, stream>>>(ys, lin_w, lin_b, out);
}

// Round 9
// 291.762 us; speedup vs baseline: 1.4476x; 1.2273x over previous
//
#include <hip/hip_runtime.h>
#include <math.h>

// Problem constants (fixed by the reference file)
#define NND 100000            // nodes
#define NED 1600000           // edges (before self-loops)
#define TOTE (NND + NED)      // edges + self-loops

#define SCAN_BS 256
#define SCAN_NB ((NND + SCAN_BS - 1) / SCAN_BS)   // 391

// dst-range-partitioned scatter (one range per XCD)
#define NRANGE 8
#define RNG_NODES ((NND + NRANGE - 1) / NRANGE)   // 12500
#define NCHUNK 640
#define CHUNK_E ((NED + NCHUNK - 1) / NCHUNK)     // 2500

// Workspace layout (bytes), total ~87.7 MB
#define OFF_HB    ((size_t)0)
#define OFF_YS    ((size_t)25600000)
#define OFF_ASRC  ((size_t)76800000)
#define OFF_ADST  ((size_t)78400000)
#define OFF_OFFS  ((size_t)80000000)
#define OFF_CNT   ((size_t)80400016)
#define OFF_SRT   ((size_t)80800016)
#define OFF_BSUM  ((size_t)87600016)
#define OFF_BPREF ((size_t)87604016)
#define OFF_WF    ((size_t)87608016)   // 2048 frags * 8 ushort = 32 KB (16B aligned)

typedef __attribute__((ext_vector_type(8))) short short8;
typedef __attribute__((ext_vector_type(4))) float f32x4;

__device__ __forceinline__ float leaky02(float v) { return v > 0.f ? v : 0.2f * v; }

// f32 -> bf16 with round-to-nearest-even
__device__ __forceinline__ unsigned short f2bf(float f) {
    unsigned u = __float_as_uint(f);
    return (unsigned short)((u + 0x7fffu + ((u >> 16) & 1u)) >> 16);
}

// ---------------------------------------------------------------------------
// CSR build (all proven r6-r8)
// ---------------------------------------------------------------------------
__global__ __launch_bounds__(256)
void k_count_init(int* __restrict__ counts) {
    const int i = blockIdx.x * 256 + threadIdx.x;
    if (i < NND) counts[i] = 1;
}

__global__ __launch_bounds__(256)
void k_hist(const int* __restrict__ edst, int* __restrict__ counts) {
    const int e = blockIdx.x * 256 + threadIdx.x;
    if (e < NED) atomicAdd(&counts[edst[e]], 1);
}

__global__ __launch_bounds__(SCAN_BS)
void k_scan_partial(const int* __restrict__ counts, int* __restrict__ bsum) {
    __shared__ int s[SCAN_BS];
    const int t = threadIdx.x;
    const int i = blockIdx.x * SCAN_BS + t;
    s[t] = (i < NND) ? counts[i] : 0;
    __syncthreads();
#pragma unroll
    for (int d = SCAN_BS / 2; d > 0; d >>= 1) {
        if (t < d) s[t] += s[t + d];
        __syncthreads();
    }
    if (t == 0) bsum[blockIdx.x] = s[0];
}

__global__ __launch_bounds__(512)
void k_scan_bsums(const int* __restrict__ bsum, int* __restrict__ bpref) {
    __shared__ int s[512];
    const int t = threadIdx.x;
    const int v0 = (t < SCAN_NB) ? bsum[t] : 0;
    s[t] = v0;
    __syncthreads();
#pragma unroll
    for (int d = 1; d < 512; d <<= 1) {
        int v = (t >= d) ? s[t - d] : 0;
        __syncthreads();
        s[t] += v;
        __syncthreads();
    }
    if (t < SCAN_NB) bpref[t] = s[t] - v0;   // exclusive
}

__global__ __launch_bounds__(SCAN_BS)
void k_scan_final(const int* __restrict__ counts, const int* __restrict__ bpref,
                  int* __restrict__ off) {
    __shared__ int s[SCAN_BS];
    const int t = threadIdx.x;
    const int i = blockIdx.x * SCAN_BS + t;
    const int v0 = (i < NND) ? counts[i] : 0;
    s[t] = v0;
    __syncthreads();
#pragma unroll
    for (int d = 1; d < SCAN_BS; d <<= 1) {
        int v = (t >= d) ? s[t - d] : 0;
        __syncthreads();
        s[t] += v;
        __syncthreads();
    }
    if (i < NND) off[i + 1] = bpref[blockIdx.x] + s[t];
    if (i == 0) off[0] = 0;
}

// Range-partitioned scatter (r8 proven: one dst-range per XCD kills the
// cross-XCD partial-line writeback amplification).
__global__ __launch_bounds__(256)
void k_scatter_rng(const int* __restrict__ esrc, const int* __restrict__ edst,
                   const int* __restrict__ off, int* __restrict__ counts,
                   int* __restrict__ ssrt)
{
    const int r = blockIdx.x % NRANGE;
    const int chunk = blockIdx.x / NRANGE;
    const int dlo = r * RNG_NODES;
    const int dhi = min(NND, dlo + RNG_NODES);

    if (chunk == 0) {   // self-loop at each segment head (same L2 range)
        for (int d = dlo + threadIdx.x; d < dhi; d += 256)
            ssrt[off[d]] = d;
    }
    const int elo = chunk * CHUNK_E;
    const int ehi = min(NED, elo + CHUNK_E);
    for (int e = elo + threadIdx.x; e < ehi; e += 256) {
        const int d = edst[e];
        if (d >= dlo && d < dhi) {
            const int pos = off[d] + atomicAdd(&counts[d], 1);
            ssrt[pos] = esrc[e];
        }
    }
}

// ---------------------------------------------------------------------------
// W pre-fragmentation: W fp32 [128][128] -> bf16 MFMA B-fragments, laid out
// lane-contiguous so gemm1 loads them as coalesced dwordx4 (L3-resident 32KB).
// Fragment id = ((wv*2+ct)*4+ks)*64 + lane; elem j: B[k=ks*32+(l>>4)*8+j]
//                                                    [col=wv*32+ct*16+(l&15)]
// ---------------------------------------------------------------------------
__global__ __launch_bounds__(256)
void k_wprep(const float* __restrict__ W, unsigned short* __restrict__ wf) {
    const int idx = blockIdx.x * 256 + threadIdx.x;   // 0..2047
    if (idx >= 2048) return;
    const int l  = idx & 63;
    const int ks = (idx >> 6) & 3;
    const int ct = (idx >> 8) & 1;
    const int wv = idx >> 9;                          // 0..3
    const int col = wv * 32 + ct * 16 + (l & 15);
    const int k0  = ks * 32 + (l >> 4) * 8;
#pragma unroll
    for (int j = 0; j < 8; ++j)
        wf[idx * 8 + j] = f2bf(W[(size_t)(k0 + j) * 128 + col]);
}

// ---------------------------------------------------------------------------
// K1 (MFMA): h = x @ W (bf16 out), fused a_src/a_dst epilogue.
// 32 rows/block, 256 threads = 4 waves; wave wv owns cols [wv*32, wv*32+32)
// = exactly head wv. Per wave: 2 row-tiles x 2 col-tiles x (K=128/32) = 16
// mfma_f32_16x16x32_bf16. x staged to LDS as bf16 with XOR swizzle
// (byte ^= (row&7)<<4): A-frag read is 16 rows at stride 256B = 16-way bank
// conflict unswizzled (G4). C/D layout (m89-verified): col=lane&15,
// row=(lane>>4)*4+reg. A/B: row/col=l&15, k=(l>>4)*8+j.
// ---------------------------------------------------------------------------
__global__ __launch_bounds__(256)
void k_gemm1(const float* __restrict__ x, const unsigned short* __restrict__ wf,
             const float* __restrict__ att_s, const float* __restrict__ att_d,
             unsigned short* __restrict__ hb,
             float* __restrict__ a_src, float* __restrict__ a_dst)
{
    __shared__ unsigned short xb[32 * 128];   // 8 KB, XOR-swizzled
    const int tid = threadIdx.x;
    const int wv = tid >> 6;          // wave = head
    const int l = tid & 63;
    const int lg = l >> 4;            // 0..3
    const int lc = l & 15;
    const int row0 = blockIdx.x * 32; // 3125 * 32 == 100000 exactly

    // ---- stage x rows -> bf16 LDS (swizzled) ----
    const float4* x4 = (const float4*)(x + (size_t)row0 * 128);
#pragma unroll
    for (int i = 0; i < 4; ++i) {
        const int g = tid + 256 * i;          // 0..1023 float4s
        const int row = g >> 5;               // local row
        const int kq = g & 31;                // float4 index in row
        const float4 v = x4[g];
        uint2 p;
        p.x = (unsigned)f2bf(v.x) | ((unsigned)f2bf(v.y) << 16);
        p.y = (unsigned)f2bf(v.z) | ((unsigned)f2bf(v.w) << 16);
        const int byteoff = (row * 256 + kq * 8) ^ ((row & 7) << 4);
        *(uint2*)((char*)xb + byteoff) = p;
    }

    // ---- load this wave's B fragments (block-invariant, L3-resident) ----
    short8 bf[2][4];
#pragma unroll
    for (int ct = 0; ct < 2; ++ct)
#pragma unroll
        for (int ks = 0; ks < 4; ++ks)
            bf[ct][ks] = *(const short8*)(wf + (size_t)((((wv * 2 + ct) * 4 + ks) * 64 + l) * 8));

    __syncthreads();

    // ---- MFMA main: acc[rt][ct] over K ----
    f32x4 acc[2][2];
#pragma unroll
    for (int rt = 0; rt < 2; ++rt)
#pragma unroll
        for (int ct = 0; ct < 2; ++ct)
            acc[rt][ct] = (f32x4){0.f, 0.f, 0.f, 0.f};

#pragma unroll
    for (int ks = 0; ks < 4; ++ks) {
        short8 a[2];
#pragma unroll
        for (int rt = 0; rt < 2; ++rt) {
            const int row = rt * 16 + lc;
            const int byteoff = (row * 256 + (ks * 32 + lg * 8) * 2) ^ ((row & 7) << 4);
            a[rt] = *(const short8*)((const char*)xb + byteoff);
        }
#pragma unroll
        for (int rt = 0; rt < 2; ++rt)
#pragma unroll
            for (int ct = 0; ct < 2; ++ct)
                acc[rt][ct] = __builtin_amdgcn_mfma_f32_16x16x32_bf16(
                    a[rt], bf[ct][ks], acc[rt][ct], 0, 0, 0);
    }

    // ---- epilogue: hb store + a_src/a_dst head-dot ----
    const int c0 = wv * 32 + lc;              // ct=0 column
    const float as0 = att_s[c0], as1 = att_s[c0 + 16];
    const float ad0 = att_d[c0], ad1 = att_d[c0 + 16];

#pragma unroll
    for (int rt = 0; rt < 2; ++rt) {
#pragma unroll
        for (int r = 0; r < 4; ++r) {
            const int row = row0 + rt * 16 + lg * 4 + r;
            const float h0 = acc[rt][0][r];
            const float h1 = acc[rt][1][r];
            hb[(size_t)row * 128 + c0]      = f2bf(h0);
            hb[(size_t)row * 128 + c0 + 16] = f2bf(h1);
            float vs = h0 * as0 + h1 * as1;
            float vd = h0 * ad0 + h1 * ad1;
#pragma unroll
            for (int o = 8; o > 0; o >>= 1) {     // reduce over lc (16 lanes)
                vs += __shfl_xor(vs, o, 64);
                vd += __shfl_xor(vd, o, 64);
            }
            if (lc == 0) {
                a_src[row * 4 + wv] = vs;
                a_dst[row * 4 + wv] = vd;
            }
        }
    }
}

// ---------------------------------------------------------------------------
// Fused segment softmax + aggregation + bias + relu. One wave per node.
// (r4 proven, frozen.)
// ---------------------------------------------------------------------------
__global__ __launch_bounds__(256)
void k_fused(const int* __restrict__ off, const int* __restrict__ ssrt,
             const float* __restrict__ a_src, const float* __restrict__ a_dst,
             const unsigned short* __restrict__ hb, const float* __restrict__ bias,
             float* __restrict__ ys)
{
    __shared__ int   s_src[4][64];
    __shared__ float s_alp[4][64][4];
    const int lane = threadIdx.x & 63;
    const int wv = threadIdx.x >> 6;
    const int d = blockIdx.x * 4 + wv;
    if (d >= NND) return;
    const int beg = off[d];
    const int deg = off[d + 1] - beg;
    const float4 ad = *(const float4*)(a_dst + (size_t)d * 4);

    int mysrc = d;
    float4 e4 = make_float4(-1e30f, -1e30f, -1e30f, -1e30f);
    if (lane < deg) {
        mysrc = ssrt[beg + lane];
        const float4 as = *(const float4*)(a_src + (size_t)mysrc * 4);
        e4.x = leaky02(as.x + ad.x);
        e4.y = leaky02(as.y + ad.y);
        e4.z = leaky02(as.z + ad.z);
        e4.w = leaky02(as.w + ad.w);
    }
    float4 mx = e4;
    for (int base = 64; base < deg; base += 64) {
        if (base + lane < deg) {
            const int s = ssrt[beg + base + lane];
            const float4 as = *(const float4*)(a_src + (size_t)s * 4);
            mx.x = fmaxf(mx.x, leaky02(as.x + ad.x));
            mx.y = fmaxf(mx.y, leaky02(as.y + ad.y));
            mx.z = fmaxf(mx.z, leaky02(as.z + ad.z));
            mx.w = fmaxf(mx.w, leaky02(as.w + ad.w));
        }
    }
#pragma unroll
    for (int o = 32; o > 0; o >>= 1) {
        mx.x = fmaxf(mx.x, __shfl_xor(mx.x, o, 64));
        mx.y = fmaxf(mx.y, __shfl_xor(mx.y, o, 64));
        mx.z = fmaxf(mx.z, __shfl_xor(mx.z, o, 64));
        mx.w = fmaxf(mx.w, __shfl_xor(mx.w, o, 64));
    }
    float4 ex = make_float4(0.f, 0.f, 0.f, 0.f);
    if (lane < deg) {
        ex.x = __expf(e4.x - mx.x);
        ex.y = __expf(e4.y - mx.y);
        ex.z = __expf(e4.z - mx.z);
        ex.w = __expf(e4.w - mx.w);
    }
    float4 sm = ex;
    for (int base = 64; base < deg; base += 64) {
        if (base + lane < deg) {
            const int s = ssrt[beg + base + lane];
            const float4 as = *(const float4*)(a_src + (size_t)s * 4);
            sm.x += __expf(leaky02(as.x + ad.x) - mx.x);
            sm.y += __expf(leaky02(as.y + ad.y) - mx.y);
            sm.z += __expf(leaky02(as.z + ad.z) - mx.z);
            sm.w += __expf(leaky02(as.w + ad.w) - mx.w);
        }
    }
#pragma unroll
    for (int o = 32; o > 0; o >>= 1) {
        sm.x += __shfl_xor(sm.x, o, 64);
        sm.y += __shfl_xor(sm.y, o, 64);
        sm.z += __shfl_xor(sm.z, o, 64);
        sm.w += __shfl_xor(sm.w, o, 64);
    }
    const float4 inv = make_float4(1.f / (sm.x + 1e-16f), 1.f / (sm.y + 1e-16f),
                                   1.f / (sm.z + 1e-16f), 1.f / (sm.w + 1e-16f));

    const int cnt = min(deg, 64);
    if (lane < cnt) {
        s_src[wv][lane] = mysrc;
        const float4 al = make_float4(ex.x * inv.x, ex.y * inv.y,
                                      ex.z * inv.z, ex.w * inv.w);
        *(float4*)&s_alp[wv][lane][0] = al;
    }

    const int hsel = lane >> 4;               // head for channels 2*lane,2*lane+1
    float accx = 0.f, accy = 0.f;
    int k = 0;
    for (; k + 4 <= cnt; k += 4) {
        const int s0 = s_src[wv][k],     s1 = s_src[wv][k + 1];
        const int s2 = s_src[wv][k + 2], s3 = s_src[wv][k + 3];
        const float A0 = s_alp[wv][k][hsel],     A1 = s_alp[wv][k + 1][hsel];
        const float A2 = s_alp[wv][k + 2][hsel], A3 = s_alp[wv][k + 3][hsel];
        const unsigned u0 = *(const unsigned*)(hb + (size_t)s0 * 128 + 2 * lane);
        const unsigned u1 = *(const unsigned*)(hb + (size_t)s1 * 128 + 2 * lane);
        const unsigned u2 = *(const unsigned*)(hb + (size_t)s2 * 128 + 2 * lane);
        const unsigned u3 = *(const unsigned*)(hb + (size_t)s3 * 128 + 2 * lane);
        accx += __uint_as_float(u0 << 16) * A0;
        accy += __uint_as_float(u0 & 0xffff0000u) * A0;
        accx += __uint_as_float(u1 << 16) * A1;
        accy += __uint_as_float(u1 & 0xffff0000u) * A1;
        accx += __uint_as_float(u2 << 16) * A2;
        accy += __uint_as_float(u2 & 0xffff0000u) * A2;
        accx += __uint_as_float(u3 << 16) * A3;
        accy += __uint_as_float(u3 & 0xffff0000u) * A3;
    }
    for (; k < cnt; ++k) {
        const int s = s_src[wv][k];
        const float A = s_alp[wv][k][hsel];
        const unsigned u = *(const unsigned*)(hb + (size_t)s * 128 + 2 * lane);
        accx += __uint_as_float(u << 16) * A;
        accy += __uint_as_float(u & 0xffff0000u) * A;
    }
    for (int base = 64; base < deg; base += 64) {
        const int c2 = min(64, deg - base);
        if (lane < c2) {
            const int s = ssrt[beg + base + lane];
            const float4 as = *(const float4*)(a_src + (size_t)s * 4);
            float4 al2;
            al2.x = __expf(leaky02(as.x + ad.x) - mx.x) * inv.x;
            al2.y = __expf(leaky02(as.y + ad.y) - mx.y) * inv.y;
            al2.z = __expf(leaky02(as.z + ad.z) - mx.z) * inv.z;
            al2.w = __expf(leaky02(as.w + ad.w) - mx.w) * inv.w;
            s_src[wv][lane] = s;
            *(float4*)&s_alp[wv][lane][0] = al2;
        }
        for (int kk = 0; kk < c2; ++kk) {
            const int s = s_src[wv][kk];
            const float A = s_alp[wv][kk][hsel];
            const unsigned u = *(const unsigned*)(hb + (size_t)s * 128 + 2 * lane);
            accx += __uint_as_float(u << 16) * A;
            accy += __uint_as_float(u & 0xffff0000u) * A;
        }
    }
    const float2 bb = *(const float2*)(bias + 2 * lane);
    float ox = accx + bb.x, oy = accy + bb.y;
    ox = ox > 0.f ? ox : 0.f;
    oy = oy > 0.f ? oy : 0.f;
    *(float2*)(ys + (size_t)d * 128 + 2 * lane) = make_float2(ox, oy);
}

// ---------------------------------------------------------------------------
// K_out: out = ys @ lin_w + lin_b  (N x 128 @ 128 x 64). (r3 proven, frozen.)
// ---------------------------------------------------------------------------
__global__ __launch_bounds__(128)
void k_out(const float* __restrict__ ys, const float* __restrict__ lin_w,
           const float* __restrict__ lin_b, float* __restrict__ out)
{
    const int t = threadIdx.x;
    const int j = t & 63;
    const int half = t >> 6;
    const int row0 = blockIdx.x * 16;    // 6250 * 16 == 100000 exactly
    __shared__ float yl[16][128];

    float w[128];
#pragma unroll
    for (int k = 0; k < 128; ++k) w[k] = lin_w[(size_t)k * 64 + j];
    const float lb = lin_b[j];

#pragma unroll 4
    for (int r = 0; r < 16; ++r)
        yl[r][t] = ys[(size_t)(row0 + r) * 128 + t];
    __syncthreads();

#pragma unroll
    for (int g = 0; g < 2; ++g) {
        const int rb = g * 8 + half;    // rows rb, rb+2, rb+4, rb+6
        float a0 = 0.f, a1 = 0.f, a2 = 0.f, a3 = 0.f;
#pragma unroll
        for (int k = 0; k < 128; ++k) {
            const float wk = w[k];
            a0 += yl[rb + 0][k] * wk;
            a1 += yl[rb + 2][k] * wk;
            a2 += yl[rb + 4][k] * wk;
            a3 += yl[rb + 6][k] * wk;
        }
        out[(size_t)(row0 + rb + 0) * 64 + j] = a0 + lb;
        out[(size_t)(row0 + rb + 2) * 64 + j] = a1 + lb;
        out[(size_t)(row0 + rb + 4) * 64 + j] = a2 + lb;
        out[(size_t)(row0 + rb + 6) * 64 + j] = a3 + lb;
    }
}

extern "C" void kernel_launch(void* const* d_in, const int* in_sizes, int n_in,
                              void* d_out, int out_size, void* d_ws, size_t ws_size,
                              hipStream_t stream)
{
    const float* x     = (const float*)d_in[0];
    const int*   ei    = (const int*)  d_in[1];   // [2][E] int32
    const float* W     = (const float*)d_in[2];
    const float* att_s = (const float*)d_in[3];
    const float* att_d = (const float*)d_in[4];
    const float* bias  = (const float*)d_in[5];
    const float* lin_w = (const float*)d_in[6];
    const float* lin_b = (const float*)d_in[7];
    float* out = (float*)d_out;

    const int* esrc = ei;        // edge_index[0] = message source
    const int* edst = ei + NED;  // edge_index[1] = message target

    char* ws = (char*)d_ws;
    unsigned short* hb = (unsigned short*)(ws + OFF_HB);
    float* ys    = (float*)(ws + OFF_YS);
    float* a_src = (float*)(ws + OFF_ASRC);
    float* a_dst = (float*)(ws + OFF_ADST);
    int*   offs  = (int*)  (ws + OFF_OFFS);
    int*   cnts  = (int*)  (ws + OFF_CNT);
    int*   ssrt  = (int*)  (ws + OFF_SRT);
    int*   bsum  = (int*)  (ws + OFF_BSUM);
    int*   bpref = (int*)  (ws + OFF_BPREF);
    unsigned short* wf = (unsigned short*)(ws + OFF_WF);

    // CSR build (dst-sorted edge list, self-loop at each segment head)
    k_count_init<<<(NND + 255) / 256, 256, 0, stream>>>(cnts);
    k_hist<<<(NED + 255) / 256, 256, 0, stream>>>(edst, cnts);
    k_scan_partial<<<SCAN_NB, SCAN_BS, 0, stream>>>(cnts, bsum);
    k_scan_bsums<<<1, 512, 0, stream>>>(bsum, bpref);
    k_scan_final<<<SCAN_NB, SCAN_BS, 0, stream>>>(cnts, bpref, offs);
    k_count_init<<<(NND + 255) / 256, 256, 0, stream>>>(cnts);  // reset cursors
    k_scatter_rng<<<NRANGE * NCHUNK, 256, 0, stream>>>(esrc, edst, offs, cnts, ssrt);

    // W -> bf16 MFMA fragments, then feature transform + attention logits
    k_wprep<<<8, 256, 0, stream>>>(W, wf);
    k_gemm1<<<NND / 32, 256, 0, stream>>>(x, wf, att_s, att_d, hb, a_src, a_dst);

    // fused segment softmax + aggregation + bias + relu
    k_fused<<<(NND + 3) / 4, 256, 0, stream>>>(offs, ssrt, a_src, a_dst, hb, bias, ys);

    // output projection
    k_out<<<NND / 16, 128, 0, stream>>>(ys, lin_w, lin_b, out);
}